// Round 24
// baseline (213.751 us; speedup 1.0000x reference)
//
#include <hip/hip_runtime.h>
#include <hip/hip_bf16.h>

#define B 16
#define L 64
#define P 1024
#define V 64
#define Q 16
#define LN64 4.158883083359672f

#define CHBC 16           // p per k_bc block
#define NCH_BC (P / CHBC) // 64

typedef unsigned short ushort8_t __attribute__((ext_vector_type(8)));
typedef __attribute__((ext_vector_type(8))) short bf16x8;
typedef __attribute__((ext_vector_type(4))) float f32x4;
typedef __attribute__((ext_vector_type(4))) unsigned int u32x4;

static __device__ __forceinline__ float bf2f(ushort u) {
    return __uint_as_float(((unsigned int)u) << 16);
}
static __device__ __forceinline__ ushort f2bf(float f) {
    unsigned int x = __float_as_uint(f);
    unsigned int r = (x + 0x7fffu + ((x >> 16) & 1u)) >> 16;
    return (ushort)r;
}
static __device__ __forceinline__ unsigned pk2(float lo, float hi) {
    return (unsigned)f2bf(lo) | ((unsigned)f2bf(hi) << 16);
}

static __device__ __forceinline__ float wsum64(float v) {
#pragma unroll
    for (int m = 32; m > 0; m >>= 1) v += __shfl_xor(v, m, 64);
    return v;
}
static __device__ __forceinline__ float wmax64(float v) {
#pragma unroll
    for (int m = 32; m > 0; m >>= 1) v = fmaxf(v, __shfl_xor(v, m, 64));
    return v;
}

union FragU { uint4 u; bf16x8 s; };

// ---------------------------------------------------------------------------
// K_uhat v23b: v22 (compiler-scheduled reg-direct MFMA, VGPR<=128) +
// NONTEMPORAL hints on its strictly-streaming traffic (round-23 retry with
// native ext_vector types -- __builtin_nontemporal_* rejects HIP_vector_type):
//  - W loads nt (read once; 256 MB stream = L3 size -> would thrash L3);
//  - uhat / sp0 stores nt (not consumed within this kernel).
// k_bc keeps DEFAULT loads so uhat lines may be L3-served between launches.
// Everything else byte-identical to v22 (204.9 us).
// ---------------------------------------------------------------------------
__global__ __launch_bounds__(256, 4) void k_uhat(const float* __restrict__ Wt,
                                                 const float* __restrict__ x,
                                                 ushort* __restrict__ uhat,
                                                 float* __restrict__ sp0) {
    const int t = threadIdx.x;
    const int w = t >> 6;
    const int lane = t & 63;
    const int kb = lane >> 4;     // k-octet (0..3); kb>=2 -> p_odd role
    const int cc = lane & 15;     // A row (v low) / D col (b)
    const int ch = blockIdx.x;    // p-chunk of 16
    const int l = blockIdx.y;
    const int p0 = ch * 16;

    __shared__ unsigned int xstage[16][32][4];   // 8 KB packed-bf16 x
    __shared__ float wred[4][16][64];            // 16 KB s0 wave partials

#pragma unroll
    for (int i = 0; i < 8; ++i) {
        const int e = i * 256 + t;        // 2048 entries
        const int pp = e >> 7, ln = (e >> 2) & 31, m = e & 3;
        const int b = ln & 15, qb = (ln >> 4) * 8;
        const float2 xv = *reinterpret_cast<const float2*>(
            x + ((size_t)b * P + p0 + pp) * Q + qb + 2 * m);
        xstage[pp][ln][m] = pk2(xv.x, xv.y);
    }
    __syncthreads();

    const float* gW = Wt + ((size_t)l * P + p0 + w * 4) * (V * Q);
    // per-lane base within pair: p_loc = 2i + (kb>>1); row v = g*16+cc; q-octet kb&1
    const float* lb = gW + (size_t)(kb >> 1) * (V * Q) + cc * Q + (kb & 1) * 8;

    f32x4 cacc0 = {0.f, 0.f, 0.f, 0.f}, cacc1 = {0.f, 0.f, 0.f, 0.f};
    f32x4 cacc2 = {0.f, 0.f, 0.f, 0.f}, cacc3 = {0.f, 0.f, 0.f, 0.f};
    f32x4 wl[2][8];

    // issue ALL W loads as nontemporal reads -- compiler schedules/waits
#pragma unroll
    for (int i = 0; i < 2; ++i) {
        const float* bp = lb + (size_t)(2 * i) * (V * Q);
#pragma unroll
        for (int g = 0; g < 4; ++g) {
            wl[i][2 * g + 0] =
                __builtin_nontemporal_load((const f32x4*)(bp + g * 256));
            wl[i][2 * g + 1] =
                __builtin_nontemporal_load((const f32x4*)(bp + g * 256 + 4));
        }
    }

#define ONEG(g_, i_, cacc_, ue_, uo_)                                         \
    {                                                                         \
        FragU wf_;                                                            \
        const f32x4 f0_ = wl[i_][2 * g_ + 0];                                 \
        const f32x4 f1_ = wl[i_][2 * g_ + 1];                                 \
        wf_.u = (uint4){pk2(f0_[0], f0_[1]), pk2(f0_[2], f0_[3]),             \
                        pk2(f1_[0], f1_[1]), pk2(f1_[2], f1_[3])};            \
        f32x4 De_ = __builtin_amdgcn_mfma_f32_16x16x32_bf16(wf_.s, axe_.s,    \
                                                            cacc_, 0, 0, 0);  \
        ue_ = De_ - cacc_;                                                    \
        f32x4 Do_ = __builtin_amdgcn_mfma_f32_16x16x32_bf16(wf_.s, axo_.s,    \
                                                            De_, 0, 0, 0);    \
        uo_ = Do_ - De_;                                                      \
        cacc_ = Do_;                                                          \
    }

#define STOREU(u0_, u1_, u2_, u3_, p_)                                        \
    {                                                                         \
        u32x4 A_, Bv_;                                                        \
        A_[0] = pk2(u0_[0], u1_[0]); A_[1] = pk2(u2_[0], u3_[0]);             \
        A_[2] = pk2(u0_[1], u1_[1]); A_[3] = pk2(u2_[1], u3_[1]);             \
        Bv_[0] = pk2(u0_[2], u1_[2]); Bv_[1] = pk2(u2_[2], u3_[2]);           \
        Bv_[2] = pk2(u0_[3], u1_[3]); Bv_[3] = pk2(u2_[3], u3_[3]);           \
        ushort* ub_ = uhat + (((size_t)l * P + (p_)) * B + cc) * V + kb * 16; \
        __builtin_nontemporal_store(A_, reinterpret_cast<u32x4*>(ub_));       \
        __builtin_nontemporal_store(Bv_, reinterpret_cast<u32x4*>(ub_ + 8));  \
    }

#pragma unroll
    for (int i = 0; i < 2; ++i) {
        // x B-frag variants read at use from persistent xstage
        FragU axe_, axo_;
        if (lane < 32)
            axe_.u = *reinterpret_cast<const uint4*>(&xstage[w * 4 + 2 * i][lane][0]);
        else
            axe_.u = (uint4){0u, 0u, 0u, 0u};
        if (lane >= 32)
            axo_.u = *reinterpret_cast<const uint4*>(&xstage[w * 4 + 2 * i + 1][lane - 32][0]);
        else
            axo_.u = (uint4){0u, 0u, 0u, 0u};

        f32x4 ue0, ue1, ue2, ue3, uo0, uo1, uo2, uo3;
        ONEG(0, i, cacc0, ue0, uo0);
        ONEG(1, i, cacc1, ue1, uo1);
        ONEG(2, i, cacc2, ue2, uo2);
        ONEG(3, i, cacc3, ue3, uo3);
        const int pe = p0 + w * 4 + 2 * i;
        STOREU(ue0, ue1, ue2, ue3, pe);
        STOREU(uo0, uo1, uo2, uo3, pe + 1);
    }
#undef ONEG
#undef STOREU

    // s0: wave partials -> LDS, block-reduce over waves -> sp0[l][ch][b][sv]
    {
        float* wb = &wred[w][cc][kb * 16];
        float4 q0 = {cacc0[0], cacc1[0], cacc2[0], cacc3[0]};
        float4 q1 = {cacc0[1], cacc1[1], cacc2[1], cacc3[1]};
        float4 q2 = {cacc0[2], cacc1[2], cacc2[2], cacc3[2]};
        float4 q3 = {cacc0[3], cacc1[3], cacc2[3], cacc3[3]};
        *reinterpret_cast<float4*>(wb + 0) = q0;
        *reinterpret_cast<float4*>(wb + 4) = q1;
        *reinterpret_cast<float4*>(wb + 8) = q2;
        *reinterpret_cast<float4*>(wb + 12) = q3;
    }
    __syncthreads();
    {
        const int o = t * 4;           // output quad: b = o>>6, sv = o&63
        const int b = o >> 6, sv = o & 63;
        const float* r0 = &wred[0][b][sv];
        const float* r1 = &wred[1][b][sv];
        const float* r2 = &wred[2][b][sv];
        const float* r3 = &wred[3][b][sv];
        f32x4 s;
        s[0] = r0[0] + r1[0] + r2[0] + r3[0];
        s[1] = r0[1] + r1[1] + r2[1] + r3[1];
        s[2] = r0[2] + r1[2] + r2[2] + r3[2];
        s[3] = r0[3] + r1[3] + r2[3] + r3[3];
        __builtin_nontemporal_store(s, reinterpret_cast<f32x4*>(
            sp0 + (((size_t)l * 64 + ch) * 16 + b) * 64 + sv));
    }
}

// ---------------------------------------------------------------------------
// K_v: generic chunk-reduce + squash (sv space). unperm=1 -> write true-v.
// ---------------------------------------------------------------------------
__global__ __launch_bounds__(256) void k_v(const float* __restrict__ sp,
                                           size_t cb, size_t cl, size_t cs,
                                           int nch, float scale, int unperm,
                                           float* __restrict__ vout,
                                           float* __restrict__ norms) {
    const int b = blockIdx.y;
    const int w = threadIdx.x >> 6, lane = threadIdx.x & 63;
    const int l = blockIdx.x * 4 + w;
    const float* p = sp + cb * b + cl * l + lane;
    float s = 0.f;
#pragma unroll 8
    for (int ch = 0; ch < nch; ++ch) s += p[(size_t)ch * cs];
    s *= scale;
    float sq = wsum64(s * s);
    float f = sqrtf(sq) / (1.0f + sq);
    const int vi = unperm ? ((lane & 3) * 16 + (lane >> 4) * 4 + ((lane >> 2) & 3))
                          : lane;
    vout[((size_t)b * L + l) * V + vi] = s * f;
    if (norms && lane == 0) norms[b * L + l] = sq / (1.0f + sq);
}

// ---------------------------------------------------------------------------
// K_bc: block = (ch of 16 p, b), 512 threads. u tile in REGISTERS.
// uhat layout [l][p][b][sv]; all v-space math in sv space (invariant).
// Default (cacheable) loads on purpose: uhat may be L3-resident between
// the two k_bc launches.
// ---------------------------------------------------------------------------
__global__ __launch_bounds__(512, 4) void k_bc(const ushort* __restrict__ uhat,
                                               const float* __restrict__ vv,
                                               float* __restrict__ bbuf,
                                               float* __restrict__ sp,
                                               float* __restrict__ Tsum,
                                               int add_prev, int do_T) {
    const int ch = blockIdx.x, b = blockIdx.y;
    const int p0 = ch * CHBC;
    const int t = threadIdx.x;
    const int w = t >> 6, lane = t & 63;
    const int pl8 = lane >> 3;
    const int vg8 = lane & 7;
    const int l0 = w * 8;

    __shared__ float vsh[L][V];
    __shared__ float bl[CHBC][L + 1];
    __shared__ float twv[8];

    {
        const float4* vvp = reinterpret_cast<const float4*>(vv + (size_t)b * L * V);
        float4* vshp = reinterpret_cast<float4*>(&vsh[0][0]);
#pragma unroll
        for (int i = 0; i < 2; ++i) vshp[t + i * 512] = vvp[t + i * 512];
    }

    const size_t LSTR = (size_t)P * B * V;   // l stride
    ushort8_t ur[8][2];
    {
        const ushort* ubase = uhat + (((size_t)l0 * P + p0 + pl8) * B + b) * V + vg8 * 8;
#pragma unroll
        for (int li = 0; li < 8; ++li) {
#pragma unroll
            for (int ph = 0; ph < 2; ++ph)
                ur[li][ph] = *reinterpret_cast<const ushort8_t*>(
                    ubase + (size_t)li * LSTR + (size_t)ph * 8 * B * V);
        }
    }
    __syncthreads();

#pragma unroll
    for (int li = 0; li < 8; ++li) {
        const int l = l0 + li;
        const float4 va = *reinterpret_cast<const float4*>(&vsh[l][vg8 * 8]);
        const float4 vb = *reinterpret_cast<const float4*>(&vsh[l][vg8 * 8 + 4]);
#pragma unroll
        for (int ph = 0; ph < 2; ++ph) {
            float d;
            d = bf2f(ur[li][ph][0]) * va.x;
            d = fmaf(bf2f(ur[li][ph][1]), va.y, d);
            d = fmaf(bf2f(ur[li][ph][2]), va.z, d);
            d = fmaf(bf2f(ur[li][ph][3]), va.w, d);
            d = fmaf(bf2f(ur[li][ph][4]), vb.x, d);
            d = fmaf(bf2f(ur[li][ph][5]), vb.y, d);
            d = fmaf(bf2f(ur[li][ph][6]), vb.z, d);
            d = fmaf(bf2f(ur[li][ph][7]), vb.w, d);
            d += __shfl_xor(d, 1, 64);
            d += __shfl_xor(d, 2, 64);
            d += __shfl_xor(d, 4, 64);
            if (vg8 == 0) bl[ph * 8 + pl8][l] = d;
        }
    }
    __syncthreads();

    float tloc = 0.f;
#pragma unroll
    for (int pi = 0; pi < 2; ++pi) {
        const int pli = w * 2 + pi;
        const int p = p0 + pli;
        float bv = bl[pli][lane];
        float* bp = bbuf + ((size_t)b * P + p) * L;
        if (add_prev) bv += bp[lane];
        bp[lane] = bv;
        float m = wmax64(bv);
        float e = __expf(bv - m);
        float ssum = wsum64(e);
        float cc = e / ssum;
        bl[pli][lane] = cc;
        if (do_T) tloc += cc * __logf(64.0f * (cc + 1e-12f));
    }
    if (do_T) {
        float dsum = wsum64(tloc);
        if (lane == 0) twv[w] = dsum;
    }
    __syncthreads();
    if (do_T && t == 0) {
        float s8 = twv[0] + twv[1] + twv[2] + twv[3] +
                   twv[4] + twv[5] + twv[6] + twv[7];
        atomicAdd(Tsum, s8 * (1.0f / LN64));
    }

    float* spb = sp + (size_t)(b * NCH_BC + ch) * L * V;
#pragma unroll
    for (int li = 0; li < 8; ++li) {
        const int l = l0 + li;
        const float cA = bl[pl8][l];
        const float cB = bl[8 + pl8][l];
        float4 pa, pb;
        pa.x = cA * bf2f(ur[li][0][0]) + cB * bf2f(ur[li][1][0]);
        pa.y = cA * bf2f(ur[li][0][1]) + cB * bf2f(ur[li][1][1]);
        pa.z = cA * bf2f(ur[li][0][2]) + cB * bf2f(ur[li][1][2]);
        pa.w = cA * bf2f(ur[li][0][3]) + cB * bf2f(ur[li][1][3]);
        pb.x = cA * bf2f(ur[li][0][4]) + cB * bf2f(ur[li][1][4]);
        pb.y = cA * bf2f(ur[li][0][5]) + cB * bf2f(ur[li][1][5]);
        pb.z = cA * bf2f(ur[li][0][6]) + cB * bf2f(ur[li][1][6]);
        pb.w = cA * bf2f(ur[li][0][7]) + cB * bf2f(ur[li][1][7]);
#pragma unroll
        for (int m = 8; m <= 32; m <<= 1) {
            pa.x += __shfl_xor(pa.x, m, 64);
            pa.y += __shfl_xor(pa.y, m, 64);
            pa.z += __shfl_xor(pa.z, m, 64);
            pa.w += __shfl_xor(pa.w, m, 64);
            pb.x += __shfl_xor(pb.x, m, 64);
            pb.y += __shfl_xor(pb.y, m, 64);
            pb.z += __shfl_xor(pb.z, m, 64);
            pb.w += __shfl_xor(pb.w, m, 64);
        }
        if (pl8 == 0) {
            *reinterpret_cast<float4*>(spb + (size_t)l * V + vg8 * 8) = pa;
            *reinterpret_cast<float4*>(spb + (size_t)l * V + vg8 * 8 + 4) = pb;
        }
    }
}

// ---------------------------------------------------------------------------
// K_final: T and D. One block, 64 threads (lane = l).
// ---------------------------------------------------------------------------
__global__ void k_final(const float* __restrict__ Tsum,
                        const float* __restrict__ norms,
                        float* __restrict__ out) {
    const int lane = threadIdx.x & 63;
    float n[B];
    float sum = 0.f;
#pragma unroll
    for (int b = 0; b < B; ++b) { n[b] = norms[b * L + lane]; sum += n[b]; }
    const float mean = sum * (1.0f / B);
    float var = 0.f;
#pragma unroll
    for (int b = 0; b < B; ++b) { float d = n[b] - mean; var = fmaf(d, d, var); }
    var *= (1.0f / B);
    float sd = sqrtf(var);
    float D = wmax64(sd);
    if (lane == 0) {
        out[B * L * V] = Tsum[0] * (1.0f / (B * P));
        out[B * L * V + 1] = D;
    }
}

extern "C" void kernel_launch(void* const* d_in, const int* in_sizes, int n_in,
                              void* d_out, int out_size, void* d_ws, size_t ws_size,
                              hipStream_t stream) {
    const float* x = (const float*)d_in[0];   // (B,P,Q)
    const float* W = (const float*)d_in[1];   // (L,P,V,Q)
    float* out = (float*)d_out;               // v (B,L,V) then T, D

    char* ws = (char*)d_ws;
    ushort* uhat = (ushort*)ws;                        // [l][p][b][sv] bf16 = 128 MB
    size_t off = (size_t)B * L * P * V * 2;
    float* spbuf = (float*)(ws + off);                 // 32 MB region:
    // sp0 [l][64][16][64] (16.7 MB) and sp [b][64][l][sv] (16.7 MB) share it
    off += (size_t)64 * 128 * 16 * 64 * 4;
    float* vbuf  = (float*)(ws + off); off += (size_t)B * L * V * 4;
    float* bbuf  = (float*)(ws + off); off += (size_t)B * P * L * 4;   // 4 MB
    float* norms = (float*)(ws + off); off += (size_t)B * L * 4;
    float* Tsum  = (float*)(ws + off); off += 256;

    hipMemsetAsync(Tsum, 0, sizeof(float), stream);

    // u_hat: compiler-scheduled reg-direct MFMA, nontemporal streams
    hipLaunchKernelGGL(k_uhat, dim3(64, 64), dim3(256), 0, stream, W, x, uhat, spbuf);
    // v0 = squash((1/64) * reduce sp0)   sp0 idx = l*65536 + ch*1024 + b*64 + sv
    hipLaunchKernelGGL(k_v, dim3(L / 4, B), dim3(256), 0, stream,
                       spbuf, (size_t)64, (size_t)65536, (size_t)1024, 64,
                       1.0f / 64.0f, 0, vbuf, (float*)nullptr);
    // b1 = v0.u ; c1 ; partial s1 -> sp[b][ch][l][sv]
    hipLaunchKernelGGL(k_bc, dim3(NCH_BC, B), dim3(512), 0, stream,
                       uhat, vbuf, bbuf, spbuf, Tsum, 0, 0);
    // v1 (sv space)
    hipLaunchKernelGGL(k_v, dim3(L / 4, B), dim3(256), 0, stream,
                       spbuf, (size_t)NCH_BC * L * V, (size_t)V, (size_t)L * V,
                       NCH_BC, 1.0f, 0, vbuf, (float*)nullptr);
    // b2 = b1 + v1.u ; c2 ; T partials ; partial s2
    hipLaunchKernelGGL(k_bc, dim3(NCH_BC, B), dim3(512), 0, stream,
                       uhat, vbuf, bbuf, spbuf, Tsum, 1, 1);
    // v2 -> out (un-permuted to true v), norms
    hipLaunchKernelGGL(k_v, dim3(L / 4, B), dim3(256), 0, stream,
                       spbuf, (size_t)NCH_BC * L * V, (size_t)V, (size_t)L * V,
                       NCH_BC, 1.0f, 1, out, norms);
    hipLaunchKernelGGL(k_final, dim3(1), dim3(64), 0, stream, Tsum, norms, out);
}

// Round 25
// 205.086 us; speedup vs baseline: 1.0422x; 1.0422x over previous
//
#include <hip/hip_runtime.h>
#include <hip/hip_bf16.h>

#define B 16
#define L 64
#define P 1024
#define V 64
#define Q 16
#define LN64 4.158883083359672f

#define CHBC 16           // p per k_bc block
#define NCH_BC (P / CHBC) // 64

typedef unsigned short ushort8_t __attribute__((ext_vector_type(8)));
typedef __attribute__((ext_vector_type(8))) short bf16x8;
typedef __attribute__((ext_vector_type(4))) float f32x4;

static __device__ __forceinline__ float bf2f(ushort u) {
    return __uint_as_float(((unsigned int)u) << 16);
}
static __device__ __forceinline__ ushort f2bf(float f) {
    unsigned int x = __float_as_uint(f);
    unsigned int r = (x + 0x7fffu + ((x >> 16) & 1u)) >> 16;
    return (ushort)r;
}
static __device__ __forceinline__ unsigned pk2(float lo, float hi) {
    return (unsigned)f2bf(lo) | ((unsigned)f2bf(hi) << 16);
}

static __device__ __forceinline__ float wsum64(float v) {
#pragma unroll
    for (int m = 32; m > 0; m >>= 1) v += __shfl_xor(v, m, 64);
    return v;
}
static __device__ __forceinline__ float wmax64(float v) {
#pragma unroll
    for (int m = 32; m > 0; m >>= 1) v = fmaxf(v, __shfl_xor(v, m, 64));
    return v;
}

union FragU { uint4 u; bf16x8 s; };

// ---------------------------------------------------------------------------
// K_uhat v22 (FINAL, measured best 204.9 us): compiler-scheduled reg-direct
// coalesced MFMA producer, VGPR <= 128 (16 waves/CU). The two levers that
// worked across 15 tested axes: (1) drop all hand s_waitcnt/sched_barrier
// and let the compiler schedule (round 21, +11 us); (2) VGPR diet under the
// 128 occupancy cliff via launch_bounds(256,4) + x-frags re-read from LDS
// at use (round 22, +6.5 us). Swapped-operand MFMA (D rows = v) + sv-
// permuted uhat[l][p][b][sv] layout give 1KB-coalesced wave stores; x B-frag
// zero for k>=16 lets one instruction load W for TWO p (lanes 0-31/32-63).
// Fused iter-0 s0 partials (k_s pass deleted).
// ---------------------------------------------------------------------------
__global__ __launch_bounds__(256, 4) void k_uhat(const float* __restrict__ Wt,
                                                 const float* __restrict__ x,
                                                 ushort* __restrict__ uhat,
                                                 float* __restrict__ sp0) {
    const int t = threadIdx.x;
    const int w = t >> 6;
    const int lane = t & 63;
    const int kb = lane >> 4;     // k-octet (0..3); kb>=2 -> p_odd role
    const int cc = lane & 15;     // A row (v low) / D col (b)
    const int ch = blockIdx.x;    // p-chunk of 16
    const int l = blockIdx.y;
    const int p0 = ch * 16;

    __shared__ unsigned int xstage[16][32][4];   // 8 KB packed-bf16 x
    __shared__ float wred[4][16][64];            // 16 KB s0 wave partials

#pragma unroll
    for (int i = 0; i < 8; ++i) {
        const int e = i * 256 + t;        // 2048 entries
        const int pp = e >> 7, ln = (e >> 2) & 31, m = e & 3;
        const int b = ln & 15, qb = (ln >> 4) * 8;
        const float2 xv = *reinterpret_cast<const float2*>(
            x + ((size_t)b * P + p0 + pp) * Q + qb + 2 * m);
        xstage[pp][ln][m] = pk2(xv.x, xv.y);
    }
    __syncthreads();

    const float* gW = Wt + ((size_t)l * P + p0 + w * 4) * (V * Q);
    // per-lane base within pair: p_loc = 2i + (kb>>1); row v = g*16+cc; q-octet kb&1
    const float* lb = gW + (size_t)(kb >> 1) * (V * Q) + cc * Q + (kb & 1) * 8;

    f32x4 cacc0 = {0.f, 0.f, 0.f, 0.f}, cacc1 = {0.f, 0.f, 0.f, 0.f};
    f32x4 cacc2 = {0.f, 0.f, 0.f, 0.f}, cacc3 = {0.f, 0.f, 0.f, 0.f};
    float4 wl[2][8];

    // issue ALL W loads as plain reads -- compiler schedules/waits (k_bc style)
#pragma unroll
    for (int i = 0; i < 2; ++i) {
        const float* bp = lb + (size_t)(2 * i) * (V * Q);
#pragma unroll
        for (int g = 0; g < 4; ++g) {
            wl[i][2 * g + 0] = *(const float4*)(bp + g * 256);
            wl[i][2 * g + 1] = *(const float4*)(bp + g * 256 + 4);
        }
    }

#define ONEG(g_, i_, cacc_, ue_, uo_)                                         \
    {                                                                         \
        FragU wf_;                                                            \
        const float4 f0_ = wl[i_][2 * g_ + 0];                                \
        const float4 f1_ = wl[i_][2 * g_ + 1];                                \
        wf_.u = (uint4){pk2(f0_.x, f0_.y), pk2(f0_.z, f0_.w),                 \
                        pk2(f1_.x, f1_.y), pk2(f1_.z, f1_.w)};                \
        f32x4 De_ = __builtin_amdgcn_mfma_f32_16x16x32_bf16(wf_.s, axe_.s,    \
                                                            cacc_, 0, 0, 0);  \
        ue_ = De_ - cacc_;                                                    \
        f32x4 Do_ = __builtin_amdgcn_mfma_f32_16x16x32_bf16(wf_.s, axo_.s,    \
                                                            De_, 0, 0, 0);    \
        uo_ = Do_ - De_;                                                      \
        cacc_ = Do_;                                                          \
    }

#define STOREU(u0_, u1_, u2_, u3_, p_)                                        \
    {                                                                         \
        uint4 A_, Bv_;                                                        \
        A_.x = pk2(u0_[0], u1_[0]); A_.y = pk2(u2_[0], u3_[0]);               \
        A_.z = pk2(u0_[1], u1_[1]); A_.w = pk2(u2_[1], u3_[1]);               \
        Bv_.x = pk2(u0_[2], u1_[2]); Bv_.y = pk2(u2_[2], u3_[2]);             \
        Bv_.z = pk2(u0_[3], u1_[3]); Bv_.w = pk2(u2_[3], u3_[3]);             \
        ushort* ub_ = uhat + (((size_t)l * P + (p_)) * B + cc) * V + kb * 16; \
        *reinterpret_cast<uint4*>(ub_) = A_;                                  \
        *reinterpret_cast<uint4*>(ub_ + 8) = Bv_;                             \
    }

#pragma unroll
    for (int i = 0; i < 2; ++i) {
        // x B-frag variants read at use from persistent xstage (saves 16 VGPR)
        FragU axe_, axo_;
        if (lane < 32)
            axe_.u = *reinterpret_cast<const uint4*>(&xstage[w * 4 + 2 * i][lane][0]);
        else
            axe_.u = (uint4){0u, 0u, 0u, 0u};
        if (lane >= 32)
            axo_.u = *reinterpret_cast<const uint4*>(&xstage[w * 4 + 2 * i + 1][lane - 32][0]);
        else
            axo_.u = (uint4){0u, 0u, 0u, 0u};

        f32x4 ue0, ue1, ue2, ue3, uo0, uo1, uo2, uo3;
        ONEG(0, i, cacc0, ue0, uo0);
        ONEG(1, i, cacc1, ue1, uo1);
        ONEG(2, i, cacc2, ue2, uo2);
        ONEG(3, i, cacc3, ue3, uo3);
        const int pe = p0 + w * 4 + 2 * i;
        STOREU(ue0, ue1, ue2, ue3, pe);
        STOREU(uo0, uo1, uo2, uo3, pe + 1);
    }
#undef ONEG
#undef STOREU

    // s0: wave partials -> LDS, block-reduce over waves -> sp0[l][ch][b][sv]
    {
        float* wb = &wred[w][cc][kb * 16];
        float4 q0 = {cacc0[0], cacc1[0], cacc2[0], cacc3[0]};
        float4 q1 = {cacc0[1], cacc1[1], cacc2[1], cacc3[1]};
        float4 q2 = {cacc0[2], cacc1[2], cacc2[2], cacc3[2]};
        float4 q3 = {cacc0[3], cacc1[3], cacc2[3], cacc3[3]};
        *reinterpret_cast<float4*>(wb + 0) = q0;
        *reinterpret_cast<float4*>(wb + 4) = q1;
        *reinterpret_cast<float4*>(wb + 8) = q2;
        *reinterpret_cast<float4*>(wb + 12) = q3;
    }
    __syncthreads();
    {
        const int o = t * 4;           // output quad: b = o>>6, sv = o&63
        const int b = o >> 6, sv = o & 63;
        const float* r0 = &wred[0][b][sv];
        const float* r1 = &wred[1][b][sv];
        const float* r2 = &wred[2][b][sv];
        const float* r3 = &wred[3][b][sv];
        float4 s;
        s.x = r0[0] + r1[0] + r2[0] + r3[0];
        s.y = r0[1] + r1[1] + r2[1] + r3[1];
        s.z = r0[2] + r1[2] + r2[2] + r3[2];
        s.w = r0[3] + r1[3] + r2[3] + r3[3];
        *reinterpret_cast<float4*>(
            sp0 + (((size_t)l * 64 + ch) * 16 + b) * 64 + sv) = s;
    }
}

// ---------------------------------------------------------------------------
// K_v: generic chunk-reduce + squash (sv space). unperm=1 -> write true-v.
// ---------------------------------------------------------------------------
__global__ __launch_bounds__(256) void k_v(const float* __restrict__ sp,
                                           size_t cb, size_t cl, size_t cs,
                                           int nch, float scale, int unperm,
                                           float* __restrict__ vout,
                                           float* __restrict__ norms) {
    const int b = blockIdx.y;
    const int w = threadIdx.x >> 6, lane = threadIdx.x & 63;
    const int l = blockIdx.x * 4 + w;
    const float* p = sp + cb * b + cl * l + lane;
    float s = 0.f;
#pragma unroll 8
    for (int ch = 0; ch < nch; ++ch) s += p[(size_t)ch * cs];
    s *= scale;
    float sq = wsum64(s * s);
    float f = sqrtf(sq) / (1.0f + sq);
    const int vi = unperm ? ((lane & 3) * 16 + (lane >> 4) * 4 + ((lane >> 2) & 3))
                          : lane;
    vout[((size_t)b * L + l) * V + vi] = s * f;
    if (norms && lane == 0) norms[b * L + l] = sq / (1.0f + sq);
}

// ---------------------------------------------------------------------------
// K_bc: block = (ch of 16 p, b), 512 threads. u tile in REGISTERS.
// uhat layout [l][p][b][sv]; all v-space math in sv space (invariant).
// ---------------------------------------------------------------------------
__global__ __launch_bounds__(512, 4) void k_bc(const ushort* __restrict__ uhat,
                                               const float* __restrict__ vv,
                                               float* __restrict__ bbuf,
                                               float* __restrict__ sp,
                                               float* __restrict__ Tsum,
                                               int add_prev, int do_T) {
    const int ch = blockIdx.x, b = blockIdx.y;
    const int p0 = ch * CHBC;
    const int t = threadIdx.x;
    const int w = t >> 6, lane = t & 63;
    const int pl8 = lane >> 3;
    const int vg8 = lane & 7;
    const int l0 = w * 8;

    __shared__ float vsh[L][V];
    __shared__ float bl[CHBC][L + 1];
    __shared__ float twv[8];

    {
        const float4* vvp = reinterpret_cast<const float4*>(vv + (size_t)b * L * V);
        float4* vshp = reinterpret_cast<float4*>(&vsh[0][0]);
#pragma unroll
        for (int i = 0; i < 2; ++i) vshp[t + i * 512] = vvp[t + i * 512];
    }

    const size_t LSTR = (size_t)P * B * V;   // l stride
    ushort8_t ur[8][2];
    {
        const ushort* ubase = uhat + (((size_t)l0 * P + p0 + pl8) * B + b) * V + vg8 * 8;
#pragma unroll
        for (int li = 0; li < 8; ++li) {
#pragma unroll
            for (int ph = 0; ph < 2; ++ph)
                ur[li][ph] = *reinterpret_cast<const ushort8_t*>(
                    ubase + (size_t)li * LSTR + (size_t)ph * 8 * B * V);
        }
    }
    __syncthreads();

#pragma unroll
    for (int li = 0; li < 8; ++li) {
        const int l = l0 + li;
        const float4 va = *reinterpret_cast<const float4*>(&vsh[l][vg8 * 8]);
        const float4 vb = *reinterpret_cast<const float4*>(&vsh[l][vg8 * 8 + 4]);
#pragma unroll
        for (int ph = 0; ph < 2; ++ph) {
            float d;
            d = bf2f(ur[li][ph][0]) * va.x;
            d = fmaf(bf2f(ur[li][ph][1]), va.y, d);
            d = fmaf(bf2f(ur[li][ph][2]), va.z, d);
            d = fmaf(bf2f(ur[li][ph][3]), va.w, d);
            d = fmaf(bf2f(ur[li][ph][4]), vb.x, d);
            d = fmaf(bf2f(ur[li][ph][5]), vb.y, d);
            d = fmaf(bf2f(ur[li][ph][6]), vb.z, d);
            d = fmaf(bf2f(ur[li][ph][7]), vb.w, d);
            d += __shfl_xor(d, 1, 64);
            d += __shfl_xor(d, 2, 64);
            d += __shfl_xor(d, 4, 64);
            if (vg8 == 0) bl[ph * 8 + pl8][l] = d;
        }
    }
    __syncthreads();

    float tloc = 0.f;
#pragma unroll
    for (int pi = 0; pi < 2; ++pi) {
        const int pli = w * 2 + pi;
        const int p = p0 + pli;
        float bv = bl[pli][lane];
        float* bp = bbuf + ((size_t)b * P + p) * L;
        if (add_prev) bv += bp[lane];
        bp[lane] = bv;
        float m = wmax64(bv);
        float e = __expf(bv - m);
        float ssum = wsum64(e);
        float cc = e / ssum;
        bl[pli][lane] = cc;
        if (do_T) tloc += cc * __logf(64.0f * (cc + 1e-12f));
    }
    if (do_T) {
        float dsum = wsum64(tloc);
        if (lane == 0) twv[w] = dsum;
    }
    __syncthreads();
    if (do_T && t == 0) {
        float s8 = twv[0] + twv[1] + twv[2] + twv[3] +
                   twv[4] + twv[5] + twv[6] + twv[7];
        atomicAdd(Tsum, s8 * (1.0f / LN64));
    }

    float* spb = sp + (size_t)(b * NCH_BC + ch) * L * V;
#pragma unroll
    for (int li = 0; li < 8; ++li) {
        const int l = l0 + li;
        const float cA = bl[pl8][l];
        const float cB = bl[8 + pl8][l];
        float4 pa, pb;
        pa.x = cA * bf2f(ur[li][0][0]) + cB * bf2f(ur[li][1][0]);
        pa.y = cA * bf2f(ur[li][0][1]) + cB * bf2f(ur[li][1][1]);
        pa.z = cA * bf2f(ur[li][0][2]) + cB * bf2f(ur[li][1][2]);
        pa.w = cA * bf2f(ur[li][0][3]) + cB * bf2f(ur[li][1][3]);
        pb.x = cA * bf2f(ur[li][0][4]) + cB * bf2f(ur[li][1][4]);
        pb.y = cA * bf2f(ur[li][0][5]) + cB * bf2f(ur[li][1][5]);
        pb.z = cA * bf2f(ur[li][0][6]) + cB * bf2f(ur[li][1][6]);
        pb.w = cA * bf2f(ur[li][0][7]) + cB * bf2f(ur[li][1][7]);
#pragma unroll
        for (int m = 8; m <= 32; m <<= 1) {
            pa.x += __shfl_xor(pa.x, m, 64);
            pa.y += __shfl_xor(pa.y, m, 64);
            pa.z += __shfl_xor(pa.z, m, 64);
            pa.w += __shfl_xor(pa.w, m, 64);
            pb.x += __shfl_xor(pb.x, m, 64);
            pb.y += __shfl_xor(pb.y, m, 64);
            pb.z += __shfl_xor(pb.z, m, 64);
            pb.w += __shfl_xor(pb.w, m, 64);
        }
        if (pl8 == 0) {
            *reinterpret_cast<float4*>(spb + (size_t)l * V + vg8 * 8) = pa;
            *reinterpret_cast<float4*>(spb + (size_t)l * V + vg8 * 8 + 4) = pb;
        }
    }
}

// ---------------------------------------------------------------------------
// K_final: T and D. One block, 64 threads (lane = l).
// ---------------------------------------------------------------------------
__global__ void k_final(const float* __restrict__ Tsum,
                        const float* __restrict__ norms,
                        float* __restrict__ out) {
    const int lane = threadIdx.x & 63;
    float n[B];
    float sum = 0.f;
#pragma unroll
    for (int b = 0; b < B; ++b) { n[b] = norms[b * L + lane]; sum += n[b]; }
    const float mean = sum * (1.0f / B);
    float var = 0.f;
#pragma unroll
    for (int b = 0; b < B; ++b) { float d = n[b] - mean; var = fmaf(d, d, var); }
    var *= (1.0f / B);
    float sd = sqrtf(var);
    float D = wmax64(sd);
    if (lane == 0) {
        out[B * L * V] = Tsum[0] * (1.0f / (B * P));
        out[B * L * V + 1] = D;
    }
}

extern "C" void kernel_launch(void* const* d_in, const int* in_sizes, int n_in,
                              void* d_out, int out_size, void* d_ws, size_t ws_size,
                              hipStream_t stream) {
    const float* x = (const float*)d_in[0];   // (B,P,Q)
    const float* W = (const float*)d_in[1];   // (L,P,V,Q)
    float* out = (float*)d_out;               // v (B,L,V) then T, D

    char* ws = (char*)d_ws;
    ushort* uhat = (ushort*)ws;                        // [l][p][b][sv] bf16 = 128 MB
    size_t off = (size_t)B * L * P * V * 2;
    float* spbuf = (float*)(ws + off);                 // 32 MB region:
    // sp0 [l][64][16][64] (16.7 MB) and sp [b][64][l][sv] (16.7 MB) share it
    off += (size_t)64 * 128 * 16 * 64 * 4;
    float* vbuf  = (float*)(ws + off); off += (size_t)B * L * V * 4;
    float* bbuf  = (float*)(ws + off); off += (size_t)B * P * L * 4;   // 4 MB
    float* norms = (float*)(ws + off); off += (size_t)B * L * 4;
    float* Tsum  = (float*)(ws + off); off += 256;

    hipMemsetAsync(Tsum, 0, sizeof(float), stream);

    // u_hat: compiler-scheduled reg-direct MFMA, VGPR<=128 (16 waves/CU)
    hipLaunchKernelGGL(k_uhat, dim3(64, 64), dim3(256), 0, stream, W, x, uhat, spbuf);
    // v0 = squash((1/64) * reduce sp0)   sp0 idx = l*65536 + ch*1024 + b*64 + sv
    hipLaunchKernelGGL(k_v, dim3(L / 4, B), dim3(256), 0, stream,
                       spbuf, (size_t)64, (size_t)65536, (size_t)1024, 64,
                       1.0f / 64.0f, 0, vbuf, (float*)nullptr);
    // b1 = v0.u ; c1 ; partial s1 -> sp[b][ch][l][sv]
    hipLaunchKernelGGL(k_bc, dim3(NCH_BC, B), dim3(512), 0, stream,
                       uhat, vbuf, bbuf, spbuf, Tsum, 0, 0);
    // v1 (sv space)
    hipLaunchKernelGGL(k_v, dim3(L / 4, B), dim3(256), 0, stream,
                       spbuf, (size_t)NCH_BC * L * V, (size_t)V, (size_t)L * V,
                       NCH_BC, 1.0f, 0, vbuf, (float*)nullptr);
    // b2 = b1 + v1.u ; c2 ; T partials ; partial s2
    hipLaunchKernelGGL(k_bc, dim3(NCH_BC, B), dim3(512), 0, stream,
                       uhat, vbuf, bbuf, spbuf, Tsum, 1, 1);
    // v2 -> out (un-permuted to true v), norms
    hipLaunchKernelGGL(k_v, dim3(L / 4, B), dim3(256), 0, stream,
                       spbuf, (size_t)NCH_BC * L * V, (size_t)V, (size_t)L * V,
                       NCH_BC, 1.0f, 1, out, norms);
    hipLaunchKernelGGL(k_final, dim3(1), dim3(64), 0, stream, Tsum, norms, out);
}